// Round 10
// baseline (1195.060 us; speedup 1.0000x reference)
//
#include <hip/hip_runtime.h>
#include <math.h>

#define BLK 256
#define CH 4096          // edges per k_bin block (staged)
#define NBMAX 1024       // max buckets (256 nodes each)

// ================= binned + CSR path =================

// zero ghist + zacc; rowptr[n] = E
__global__ void k_init0(int* __restrict__ ghist, float* __restrict__ zacc,
                        int* __restrict__ rowptr, int nb, int ng, int n, int E,
                        int primary) {
  int i = blockIdx.x * BLK + threadIdx.x;
  if (i < nb) ghist[i] = 0;
  if (i < ng) zacc[i] = 0.f;
  if (primary && i == 0) rowptr[n] = E;
}

// per-bucket histogram of dst>>8 (int4 fast path)
__global__ void k_hist(const int* __restrict__ dst, int* __restrict__ ghist,
                       int E, int nb, int chunk) {
  __shared__ int h[NBMAX];
  for (int i = threadIdx.x; i < NBMAX; i += BLK) h[i] = 0;
  __syncthreads();
  long long s0 = (long long)blockIdx.x * chunk;
  int c = (int)min((long long)chunk, (long long)E - s0);
  if (c == chunk && (chunk & 3) == 0) {
    const int4* d4 = (const int4*)(dst + s0);
    int m = chunk >> 2;
    for (int i = threadIdx.x; i < m; i += BLK) {
      int4 v = d4[i];
      atomicAdd(&h[v.x >> 8], 1); atomicAdd(&h[v.y >> 8], 1);
      atomicAdd(&h[v.z >> 8], 1); atomicAdd(&h[v.w >> 8], 1);
    }
  } else {
    for (int i = threadIdx.x; i < c; i += BLK)
      atomicAdd(&h[dst[s0 + i] >> 8], 1);
  }
  __syncthreads();
  for (int b = threadIdx.x; b < nb; b += BLK)
    if (h[b]) atomicAdd(&ghist[b], h[b]);
}

// exclusive scan of ghist -> base[0..nb], cursor=base
__global__ void k_scan(const int* __restrict__ ghist, int* __restrict__ base,
                       int* __restrict__ cursor, int nb, int E) {
  __shared__ int temp[BLK];
  int t = threadIdx.x;
  int v[4]; int sm = 0;
  #pragma unroll
  for (int k = 0; k < 4; ++k) {
    int idx = t * 4 + k;
    v[k] = (idx < nb) ? ghist[idx] : 0;
    sm += v[k];
  }
  temp[t] = sm; __syncthreads();
  int inc = sm;
  for (int off = 1; off < BLK; off <<= 1) {
    int u = (t >= off) ? temp[t - off] : 0; __syncthreads();
    inc += u; temp[t] = inc; __syncthreads();
  }
  int run = inc - sm;
  #pragma unroll
  for (int k = 0; k < 4; ++k) {
    int idx = t * 4 + k;
    if (idx < nb) { base[idx] = run; cursor[idx] = run; }
    run += v[k];
  }
  if (t == BLK - 1) base[nb] = E;
}

// bin edges into per-bucket segments, rec = (src<<8)|(dst&255)
// staged in LDS; flush via slot->bucket u16 map (no binary search)
__global__ void k_bin(const int* __restrict__ src, const int* __restrict__ dst,
                      int* __restrict__ cursor, int* __restrict__ binned,
                      int E, int nb) {
  __shared__ int cb[NBMAX + 1];          // counts -> scanned local base
  __shared__ int cur[NBMAX];
  __shared__ int gofs[NBMAX];            // global ofs -> delta (gofs - base)
  __shared__ int temp[BLK];
  __shared__ int stage[CH];
  __shared__ unsigned short bkt[CH];     // slot -> bucket
  int t = threadIdx.x;
  for (int i = t; i < NBMAX; i += BLK) { cb[i] = 0; cur[i] = 0; }
  __syncthreads();
  long long s0 = (long long)blockIdx.x * CH;
  int c = (int)min((long long)CH, (long long)E - s0);
  // count
  if (c == CH) {
    const int4* d4 = (const int4*)(dst + s0);
    for (int i = t; i < (CH >> 2); i += BLK) {
      int4 v = d4[i];
      atomicAdd(&cb[v.x >> 8], 1); atomicAdd(&cb[v.y >> 8], 1);
      atomicAdd(&cb[v.z >> 8], 1); atomicAdd(&cb[v.w >> 8], 1);
    }
  } else {
    for (int i = t; i < c; i += BLK) atomicAdd(&cb[dst[s0 + i] >> 8], 1);
  }
  __syncthreads();
  // counts to registers
  int v[4];
  #pragma unroll
  for (int k = 0; k < 4; ++k) v[k] = cb[t * 4 + k];
  int sm = v[0] + v[1] + v[2] + v[3];
  temp[t] = sm; __syncthreads();
  int inc = sm;
  for (int off = 1; off < BLK; off <<= 1) {
    int u = (t >= off) ? temp[t - off] : 0; __syncthreads();
    inc += u; temp[t] = inc; __syncthreads();
  }
  // reserve global ranges from register counts
  #pragma unroll
  for (int k = 0; k < 4; ++k) {
    int b = t * 4 + k;
    if (v[k]) gofs[b] = atomicAdd(&cursor[b], v[k]);
  }
  // overwrite cb with scanned local bases
  int run = inc - sm;
  #pragma unroll
  for (int k = 0; k < 4; ++k) { cb[t * 4 + k] = run; run += v[k]; }
  if (t == BLK - 1) cb[NBMAX] = c;
  __syncthreads();
  // delta + slot->bucket map (run fill, no atomics)
  #pragma unroll
  for (int k = 0; k < 4; ++k) {
    int b = t * 4 + k;
    int s_ = cb[b], e_ = cb[b + 1];
    if (e_ > s_) {
      gofs[b] -= s_;
      for (int i = s_; i < e_; ++i) bkt[i] = (unsigned short)b;
    }
  }
  __syncthreads();
  // place into stage
  if (c == CH) {
    const int4* d4 = (const int4*)(dst + s0);
    const int4* s4 = (const int4*)(src + s0);
    for (int i = t; i < (CH >> 2); i += BLK) {
      int4 dv = d4[i]; int4 sv = s4[i];
      int b, r;
      b = dv.x >> 8; r = atomicAdd(&cur[b], 1); stage[cb[b] + r] = (sv.x << 8) | (dv.x & 255);
      b = dv.y >> 8; r = atomicAdd(&cur[b], 1); stage[cb[b] + r] = (sv.y << 8) | (dv.y & 255);
      b = dv.z >> 8; r = atomicAdd(&cur[b], 1); stage[cb[b] + r] = (sv.z << 8) | (dv.z & 255);
      b = dv.w >> 8; r = atomicAdd(&cur[b], 1); stage[cb[b] + r] = (sv.w << 8) | (dv.w & 255);
    }
  } else {
    for (int i = t; i < c; i += BLK) {
      int d = dst[s0 + i];
      int b = d >> 8;
      int r = atomicAdd(&cur[b], 1);
      stage[cb[b] + r] = (src[s0 + i] << 8) | (d & 255);
    }
  }
  __syncthreads();
  // flush: stage order -> contiguous per-run global writes
  for (int i = t; i < c; i += BLK) {
    int b = bkt[i];
    binned[(size_t)i + gofs[b]] = stage[i];
  }
}

// per-bucket counting sort: binned run -> csr (per-node grouped), rowptr, dis
__global__ void k_sortdis(const int* __restrict__ base, const int* __restrict__ binned,
                          int* __restrict__ csr, int* __restrict__ rowptr,
                          float* __restrict__ dis, int n) {
  __shared__ int cnt[256], loff[256], cur[256], temp[BLK];
  int b = blockIdx.x, t = threadIdx.x;
  cnt[t] = 0; cur[t] = 0;
  __syncthreads();
  int s = base[b], e = base[b + 1];
  for (int i = s + t; i < e; i += BLK) atomicAdd(&cnt[binned[i] & 255], 1);
  __syncthreads();
  int v = cnt[t];
  temp[t] = v; __syncthreads();
  int inc = v;
  for (int off = 1; off < BLK; off <<= 1) {
    int u = (t >= off) ? temp[t - off] : 0; __syncthreads();
    inc += u; temp[t] = inc; __syncthreads();
  }
  loff[t] = inc - v;
  int node = b * 256 + t;
  if (node < n) {
    rowptr[node] = s + inc - v;
    dis[node] = rsqrtf((float)(v + 1));   // +1 self-loop
  }
  __syncthreads();
  for (int i = s + t; i < e; i += BLK) {
    int rec = binned[i];
    int L = rec & 255;
    int p = atomicAdd(&cur[L], 1);
    csr[s + loff[L] + p] = rec >> 8;
  }
}

// fused gather + mid layer: y2 = dis*(relu(dis*(acc+y)+b1) @ W2)
// wave-per-node: 64 lanes = 32 edges x 2 float4-halves
__global__ void k_gmid(const int* __restrict__ rowptr, const int* __restrict__ csr,
                       const float* __restrict__ y, float* __restrict__ y2,
                       const float* __restrict__ dis, const float* __restrict__ W2,
                       const float* __restrict__ b1, int n) {
  __shared__ float sW[64], sb[8];
  if (threadIdx.x < 64) sW[threadIdx.x] = W2[threadIdx.x];
  if (threadIdx.x < 8)  sb[threadIdx.x] = b1[threadIdx.x];
  __syncthreads();
  int node = (int)(((long long)blockIdx.x * BLK + threadIdx.x) >> 6);
  if (node >= n) return;
  int lane = threadIdx.x & 63;
  int e = lane & 31, fq = lane >> 5;
  int start = rowptr[node], end = rowptr[node + 1];
  float4 s = make_float4(0.f, 0.f, 0.f, 0.f);
  int k = start + e;
  int sidx = (k < end) ? csr[k] : -1;
  for (int k0 = start; k0 < end; k0 += 32) {
    int nk = k0 + 32 + e;
    int nsidx = (nk < end) ? csr[nk] : -1;
    if (sidx >= 0) {
      const float4 v = *(const float4*)(y + (size_t)sidx * 8 + fq * 4);
      s.x += v.x; s.y += v.y; s.z += v.z; s.w += v.w;
    }
    sidx = nsidx;
  }
  #pragma unroll
  for (int m = 1; m <= 16; m <<= 1) {
    s.x += __shfl_xor(s.x, m);
    s.y += __shfl_xor(s.y, m);
    s.z += __shfl_xor(s.z, m);
    s.w += __shfl_xor(s.w, m);
  }
  // lanes<32 hold acc[0:4]; fetch acc[4:8] from upper half
  float h0 = __shfl(s.x, lane | 32);
  float h1 = __shfl(s.y, lane | 32);
  float h2 = __shfl(s.z, lane | 32);
  float h3 = __shfl(s.w, lane | 32);
  int j = lane;   // only j<8 meaningful
  float accj = (j == 0) ? s.x : (j == 1) ? s.y : (j == 2) ? s.z : (j == 3) ? s.w
             : (j == 4) ? h0  : (j == 5) ? h1  : (j == 6) ? h2  : h3;
  float dsv = dis[node];
  float yj = (lane < 8) ? y[(size_t)node * 8 + lane] : 0.f;
  float bj = (lane < 8) ? sb[lane] : 0.f;
  float hv = fmaxf(fmaf(dsv, accj + yj, bj), 0.f);
  float o = 0.f;
  #pragma unroll
  for (int kk = 0; kk < 8; ++kk) {
    float hk = __shfl(hv, kk);
    if (lane < 8) o = fmaf(hk, sW[kk * 8 + lane], o);
  }
  if (lane < 8) y2[(size_t)node * 8 + lane] = dsv * o;
}

// fused gather + final: z = relu(dis*(acc+y2)+b2) . Wl ; zacc[batch] += z
__global__ void k_gfin(const int* __restrict__ rowptr, const int* __restrict__ csr,
                       const float* __restrict__ y2, const float* __restrict__ dis,
                       const float* __restrict__ b2, const float* __restrict__ Wl,
                       const int* __restrict__ batch, float* __restrict__ zacc, int n) {
  __shared__ float sb[8], sw[8];
  if (threadIdx.x < 8) { sb[threadIdx.x] = b2[threadIdx.x]; sw[threadIdx.x] = Wl[threadIdx.x]; }
  __syncthreads();
  int node = (int)(((long long)blockIdx.x * BLK + threadIdx.x) >> 6);
  if (node >= n) return;
  int lane = threadIdx.x & 63;
  int e = lane & 31, fq = lane >> 5;
  int start = rowptr[node], end = rowptr[node + 1];
  float4 s = make_float4(0.f, 0.f, 0.f, 0.f);
  int k = start + e;
  int sidx = (k < end) ? csr[k] : -1;
  for (int k0 = start; k0 < end; k0 += 32) {
    int nk = k0 + 32 + e;
    int nsidx = (nk < end) ? csr[nk] : -1;
    if (sidx >= 0) {
      const float4 v = *(const float4*)(y2 + (size_t)sidx * 8 + fq * 4);
      s.x += v.x; s.y += v.y; s.z += v.z; s.w += v.w;
    }
    sidx = nsidx;
  }
  #pragma unroll
  for (int m = 1; m <= 16; m <<= 1) {
    s.x += __shfl_xor(s.x, m);
    s.y += __shfl_xor(s.y, m);
    s.z += __shfl_xor(s.z, m);
    s.w += __shfl_xor(s.w, m);
  }
  float h0 = __shfl(s.x, lane | 32);
  float h1 = __shfl(s.y, lane | 32);
  float h2 = __shfl(s.z, lane | 32);
  float h3 = __shfl(s.w, lane | 32);
  int j = lane;
  float accj = (j == 0) ? s.x : (j == 1) ? s.y : (j == 2) ? s.z : (j == 3) ? s.w
             : (j == 4) ? h0  : (j == 5) ? h1  : (j == 6) ? h2  : h3;
  float dsv = dis[node];
  float yj = (lane < 8) ? y2[(size_t)node * 8 + lane] : 0.f;
  float bj = (lane < 8) ? sb[lane] : 0.f;
  float wj = (lane < 8) ? sw[lane] : 0.f;
  float p = fmaxf(fmaf(dsv, accj + yj, bj), 0.f) * wj;
  p += __shfl_xor(p, 1);
  p += __shfl_xor(p, 2);
  p += __shfl_xor(p, 4);
  if (lane == 0) unsafeAtomicAdd(&zacc[batch[node]], p);
}

// ================= tier-2 fallback (R5 proven) =================

__global__ void k_degdis(const int* __restrict__ base, const int* __restrict__ binned,
                         float* __restrict__ dis, int n) {
  __shared__ int deg[256];
  int b = blockIdx.x, t = threadIdx.x;
  deg[t] = 1;
  __syncthreads();
  int s = base[b], e = base[b + 1];
  for (int i = s + t; i < e; i += BLK) atomicAdd(&deg[binned[i] & 255], 1);
  __syncthreads();
  int node = b * 256 + t;
  if (node < n) dis[node] = rsqrtf((float)deg[t]);
}

__global__ void k_acc(const int* __restrict__ base, const int* __restrict__ binned,
                      const float* __restrict__ y, float* __restrict__ acc, int n) {
  __shared__ float fa[2048];
  int b = blockIdx.x, t = threadIdx.x;
  for (int i = t; i < 2048; i += BLK) fa[i] = 0.f;
  __syncthreads();
  int s = base[b], e = base[b + 1];
  int j = t & 7;
  for (int i = s + (t >> 3); i < e; i += 32) {
    int rec = binned[i];
    atomicAdd(&fa[(rec & 255) * 8 + j], y[(size_t)(rec >> 8) * 8 + j]);
  }
  __syncthreads();
  int node0 = b * 256;
  int lim = (n - node0 < 256 ? n - node0 : 256) * 8;
  for (int i = t; i < lim; i += BLK) acc[(size_t)node0 * 8 + i] = fa[i];
}

// ================= dense stages =================

__global__ void k_y1n(const float* __restrict__ x, const float* __restrict__ W1,
                      const float* __restrict__ dis, float* __restrict__ y, int n) {
  __shared__ float sW[128];
  if (threadIdx.x < 128) sW[threadIdx.x] = W1[threadIdx.x];
  __syncthreads();
  int i = blockIdx.x * BLK + threadIdx.x;
  if (i >= n) return;
  const float4* xp = (const float4*)(x + (size_t)i * 16);
  float4 a = xp[0], bb = xp[1], cc = xp[2], d4 = xp[3];
  float xv[16] = {a.x,a.y,a.z,a.w, bb.x,bb.y,bb.z,bb.w,
                  cc.x,cc.y,cc.z,cc.w, d4.x,d4.y,d4.z,d4.w};
  float ds = dis[i];
  float o[8];
  #pragma unroll
  for (int jj = 0; jj < 8; ++jj) {
    float s = 0.f;
    #pragma unroll
    for (int k = 0; k < 16; ++k) s = fmaf(xv[k], sW[k*8 + jj], s);
    o[jj] = ds * s;
  }
  float4* yp = (float4*)(y + (size_t)i * 8);
  yp[0] = make_float4(o[0], o[1], o[2], o[3]);
  yp[1] = make_float4(o[4], o[5], o[6], o[7]);
}

__global__ void k_mid(const float* __restrict__ dis, float* __restrict__ y,
                      float* __restrict__ acc, const float* __restrict__ W2,
                      const float* __restrict__ b1, int n, int zero_acc) {
  __shared__ float sW[64];
  __shared__ float sb[8];
  if (threadIdx.x < 64) sW[threadIdx.x] = W2[threadIdx.x];
  if (threadIdx.x < 8)  sb[threadIdx.x] = b1[threadIdx.x];
  __syncthreads();
  int i = blockIdx.x * BLK + threadIdx.x;
  if (i >= n) return;
  float d = dis[i];
  float4* yp = (float4*)(y + (size_t)i * 8);
  float4* ap = (float4*)(acc + (size_t)i * 8);
  float4 y0 = yp[0], y1v = yp[1], a0 = ap[0], a1 = ap[1];
  float yy[8] = {y0.x,y0.y,y0.z,y0.w, y1v.x,y1v.y,y1v.z,y1v.w};
  float aa[8] = {a0.x,a0.y,a0.z,a0.w, a1.x,a1.y,a1.z,a1.w};
  float hv[8];
  #pragma unroll
  for (int jj = 0; jj < 8; ++jj) hv[jj] = fmaxf(fmaf(d, yy[jj] + aa[jj], sb[jj]), 0.f);
  float o[8];
  #pragma unroll
  for (int jj = 0; jj < 8; ++jj) {
    float s = 0.f;
    #pragma unroll
    for (int k = 0; k < 8; ++k) s = fmaf(hv[k], sW[k*8 + jj], s);
    o[jj] = d * s;
  }
  yp[0] = make_float4(o[0], o[1], o[2], o[3]);
  yp[1] = make_float4(o[4], o[5], o[6], o[7]);
  if (zero_acc) {
    ap[0] = make_float4(0.f, 0.f, 0.f, 0.f);
    ap[1] = make_float4(0.f, 0.f, 0.f, 0.f);
  }
}

__global__ void k_final(const float* __restrict__ dis, const float* __restrict__ y,
                        const float* __restrict__ acc, const float* __restrict__ b2,
                        const float* __restrict__ Wl, const int* __restrict__ batch,
                        float* __restrict__ zacc, int n) {
  __shared__ float sb[8], sw[8];
  if (threadIdx.x < 8) { sb[threadIdx.x] = b2[threadIdx.x]; sw[threadIdx.x] = Wl[threadIdx.x]; }
  __syncthreads();
  int i = blockIdx.x * BLK + threadIdx.x;
  float s = 0.f;
  int g = -1;
  if (i < n) {
    float d = dis[i];
    const float4* yp = (const float4*)(y + (size_t)i * 8);
    const float4* ap = (const float4*)(acc + (size_t)i * 8);
    float4 y0 = yp[0], y1v = yp[1], a0 = ap[0], a1 = ap[1];
    float yy[8] = {y0.x,y0.y,y0.z,y0.w, y1v.x,y1v.y,y1v.z,y1v.w};
    float aa[8] = {a0.x,a0.y,a0.z,a0.w, a1.x,a1.y,a1.z,a1.w};
    #pragma unroll
    for (int jj = 0; jj < 8; ++jj) {
      float h = fmaxf(fmaf(d, yy[jj] + aa[jj], sb[jj]), 0.f);
      s = fmaf(h, sw[jj], s);
    }
    g = batch[i];
  }
  int g0 = __shfl(g, 0);
  bool uni = __all(g == g0);
  if (uni) {
    #pragma unroll
    for (int off = 32; off > 0; off >>= 1) s += __shfl_down(s, off);
    if ((threadIdx.x & 63) == 0 && g0 >= 0) unsafeAtomicAdd(&zacc[g0], s);
  } else if (i < n) {
    unsafeAtomicAdd(&zacc[g], s);
  }
}

__global__ void k_out(const float* __restrict__ zacc, const float* __restrict__ bl,
                      float* __restrict__ out, int ng) {
  int i = blockIdx.x * BLK + threadIdx.x;
  if (i < ng) {
    float z = zacc[i] + bl[0];
    float r;
    if (z >= 0.f) { r = 1.f / (1.f + expf(-z)); }
    else          { float e = expf(z); r = e / (1.f + e); }
    out[i] = r;
  }
}

// ================= tier-3 fallback (R2 proven) =================

__global__ void k_init(int* __restrict__ deg, float* __restrict__ acc,
                       float* __restrict__ zacc, int n, int accn, int ng) {
  int jj = blockIdx.x * BLK + threadIdx.x;
  if (jj < accn) acc[jj] = 0.f;
  if (jj < n) deg[jj] = 1;
  if (jj < ng) zacc[jj] = 0.f;
}

__global__ void k_deg(const int* __restrict__ dst, int* __restrict__ deg, int E) {
  int i = blockIdx.x * BLK + threadIdx.x;
  if (i < E) atomicAdd(&deg[dst[i]], 1);
}

__global__ void k_y1(const float* __restrict__ x, const float* __restrict__ W1,
                     int* __restrict__ degdis, float* __restrict__ y, int n) {
  __shared__ float sW[128];
  if (threadIdx.x < 128) sW[threadIdx.x] = W1[threadIdx.x];
  __syncthreads();
  int i = blockIdx.x * BLK + threadIdx.x;
  if (i >= n) return;
  const float4* xp = (const float4*)(x + (size_t)i * 16);
  float4 a = xp[0], bb = xp[1], cc = xp[2], d4 = xp[3];
  float xv[16] = {a.x,a.y,a.z,a.w, bb.x,bb.y,bb.z,bb.w,
                  cc.x,cc.y,cc.z,cc.w, d4.x,d4.y,d4.z,d4.w};
  float ds = rsqrtf((float)degdis[i]);
  float o[8];
  #pragma unroll
  for (int jj = 0; jj < 8; ++jj) {
    float s = 0.f;
    #pragma unroll
    for (int k = 0; k < 16; ++k) s = fmaf(xv[k], sW[k*8 + jj], s);
    o[jj] = ds * s;
  }
  ((float*)degdis)[i] = ds;
  float4* yp = (float4*)(y + (size_t)i * 8);
  yp[0] = make_float4(o[0], o[1], o[2], o[3]);
  yp[1] = make_float4(o[4], o[5], o[6], o[7]);
}

__global__ void k_scatter(const int* __restrict__ src, const int* __restrict__ dst,
                          const float* __restrict__ y, float* __restrict__ acc,
                          long long total) {
  long long t = (long long)blockIdx.x * BLK + threadIdx.x;
  if (t >= total) return;
  int e = (int)(t >> 3);
  int h = (int)(t & 7);
  int s = src[e], d = dst[e];
  unsafeAtomicAdd(&acc[(size_t)d * 8 + h], y[(size_t)s * 8 + h]);
}

// ================= host =================

static inline size_t alignup(size_t v) { return (v + 255) & ~(size_t)255; }

extern "C" void kernel_launch(void* const* d_in, const int* in_sizes, int n_in,
                              void* d_out, int out_size, void* d_ws, size_t ws_size,
                              hipStream_t stream) {
  const float* x   = (const float*)d_in[0];
  const int*   ei  = (const int*)  d_in[1];
  const int*   bat = (const int*)  d_in[2];
  const float* W1  = (const float*)d_in[3];
  const float* b1  = (const float*)d_in[4];
  const float* W2  = (const float*)d_in[5];
  const float* b2  = (const float*)d_in[6];
  const float* Wl  = (const float*)d_in[7];
  const float* bl  = (const float*)d_in[8];
  float* out = (float*)d_out;

  int n  = in_sizes[0] / 16;   // 250000
  int E  = in_sizes[1] / 2;    // 8000000
  int ng = out_size;           // 512

  const int* src = ei;
  const int* dst = ei + E;

  int nb = (n + 255) >> 8;     // 977

  char* wsb = (char*)d_ws;
  size_t offY  = alignup((size_t)n * 4);                  // dis
  size_t offA  = offY + alignup((size_t)n * 8 * 4);       // y
  size_t offZ  = offA + alignup((size_t)n * 8 * 4);       // acc / y2
  size_t offH  = offZ + alignup((size_t)ng * 4);          // zacc
  size_t offB  = offH + alignup((size_t)NBMAX * 4);       // ghist
  size_t offCu = offB + alignup((size_t)(NBMAX + 1) * 4); // base
  size_t offBn = offCu + alignup((size_t)NBMAX * 4);      // cursor
  size_t offRp = offBn + alignup((size_t)E * 4);          // binned
  size_t offCs = offRp + alignup(((size_t)n + 1) * 4);    // rowptr
  size_t need1 = offCs + alignup((size_t)E * 4);          // csr
  size_t need2 = offRp;                                   // tier-2: through binned

  float* dis    = (float*)wsb;
  int*   deg    = (int*)wsb;
  float* y      = (float*)(wsb + offY);
  float* acc    = (float*)(wsb + offA);   // y2 alias in tier-1
  float* zacc   = (float*)(wsb + offZ);
  int*   ghist  = (int*)(wsb + offH);
  int*   base   = (int*)(wsb + offB);
  int*   cursor = (int*)(wsb + offCu);
  int*   binned = (int*)(wsb + offBn);
  int*   rowptr = (int*)(wsb + offRp);
  int*   csr    = (int*)(wsb + offCs);

  int gN = (n + BLK - 1) / BLK;
  int gG = (ng + BLK - 1) / BLK;
  int gW = (int)(((long long)n * 64 + BLK - 1) / BLK);   // wave-per-node

  bool ok_bin = (nb <= NBMAX) && (n < (1 << 23));
  bool tier1 = ok_bin && (ws_size >= need1);
  bool tier2 = ok_bin && (ws_size >= need2);

  if (tier1 || tier2) {
    int histChunk = 8192;
    int gHist = (int)(((long long)E + histChunk - 1) / histChunk);
    int gBin  = (int)(((long long)E + CH - 1) / CH);
    int gI0   = (NBMAX > ng ? NBMAX : ng) / BLK + 1;
    k_init0 <<<gI0, BLK, 0, stream>>>(ghist, zacc, rowptr, NBMAX, ng, n, E, tier1 ? 1 : 0);
    k_hist  <<<gHist, BLK, 0, stream>>>(dst, ghist, E, nb, histChunk);
    k_scan  <<<1, BLK, 0, stream>>>(ghist, base, cursor, nb, E);
    k_bin   <<<gBin, BLK, 0, stream>>>(src, dst, cursor, binned, E, nb);
    if (tier1) {
      k_sortdis<<<nb, BLK, 0, stream>>>(base, binned, csr, rowptr, dis, n);
      k_y1n   <<<gN, BLK, 0, stream>>>(x, W1, dis, y, n);
      k_gmid  <<<gW, BLK, 0, stream>>>(rowptr, csr, y, acc, dis, W2, b1, n);
      k_gfin  <<<gW, BLK, 0, stream>>>(rowptr, csr, acc, dis, b2, Wl, bat, zacc, n);
    } else {
      k_degdis<<<nb, BLK, 0, stream>>>(base, binned, dis, n);
      k_y1n   <<<gN, BLK, 0, stream>>>(x, W1, dis, y, n);
      k_acc   <<<nb, BLK, 0, stream>>>(base, binned, y, acc, n);
      k_mid   <<<gN, BLK, 0, stream>>>(dis, y, acc, W2, b1, n, 0);
      k_acc   <<<nb, BLK, 0, stream>>>(base, binned, y, acc, n);
      k_final <<<gN, BLK, 0, stream>>>(dis, y, acc, b2, Wl, bat, zacc, n);
    }
  } else {
    int accn = n * 8;
    long long tot = (long long)E * 8;
    int gInit = (accn + BLK - 1) / BLK;
    int gE    = (E + BLK - 1) / BLK;
    int gS    = (int)((tot + BLK - 1) / BLK);
    k_init   <<<gInit, BLK, 0, stream>>>(deg, acc, zacc, n, accn, ng);
    k_deg    <<<gE, BLK, 0, stream>>>(dst, deg, E);
    k_y1     <<<gN, BLK, 0, stream>>>(x, W1, deg, y, n);
    k_scatter<<<gS, BLK, 0, stream>>>(src, dst, y, acc, tot);
    k_mid    <<<gN, BLK, 0, stream>>>(dis, y, acc, W2, b1, n, 1);
    k_scatter<<<gS, BLK, 0, stream>>>(src, dst, y, acc, tot);
    k_final  <<<gN, BLK, 0, stream>>>(dis, y, acc, b2, Wl, bat, zacc, n);
  }
  k_out<<<gG, BLK, 0, stream>>>(zacc, bl, out, ng);
}

// Round 11
// 548.351 us; speedup vs baseline: 2.1794x; 2.1794x over previous
//
#include <hip/hip_runtime.h>
#include <math.h>

#define BLK 256
#define CH 4096          // edges per k_bin block (staged)
#define NBMAX 1024       // max buckets (256 nodes each)

// ================= binned + CSR path =================

// zero ghist + zacc; rowptr[n] = E
__global__ void k_init0(int* __restrict__ ghist, float* __restrict__ zacc,
                        int* __restrict__ rowptr, int nb, int ng, int n, int E,
                        int primary) {
  int i = blockIdx.x * BLK + threadIdx.x;
  if (i < nb) ghist[i] = 0;
  if (i < ng) zacc[i] = 0.f;
  if (primary && i == 0) rowptr[n] = E;
}

// per-bucket histogram of dst>>8 (int4 fast path)
__global__ void k_hist(const int* __restrict__ dst, int* __restrict__ ghist,
                       int E, int nb, int chunk) {
  __shared__ int h[NBMAX];
  for (int i = threadIdx.x; i < NBMAX; i += BLK) h[i] = 0;
  __syncthreads();
  long long s0 = (long long)blockIdx.x * chunk;
  int c = (int)min((long long)chunk, (long long)E - s0);
  if (c == chunk && (chunk & 3) == 0) {
    const int4* d4 = (const int4*)(dst + s0);
    int m = chunk >> 2;
    for (int i = threadIdx.x; i < m; i += BLK) {
      int4 v = d4[i];
      atomicAdd(&h[v.x >> 8], 1); atomicAdd(&h[v.y >> 8], 1);
      atomicAdd(&h[v.z >> 8], 1); atomicAdd(&h[v.w >> 8], 1);
    }
  } else {
    for (int i = threadIdx.x; i < c; i += BLK)
      atomicAdd(&h[dst[s0 + i] >> 8], 1);
  }
  __syncthreads();
  for (int b = threadIdx.x; b < nb; b += BLK)
    if (h[b]) atomicAdd(&ghist[b], h[b]);
}

// exclusive scan of ghist -> base[0..nb], cursor=base
__global__ void k_scan(const int* __restrict__ ghist, int* __restrict__ base,
                       int* __restrict__ cursor, int nb, int E) {
  __shared__ int temp[BLK];
  int t = threadIdx.x;
  int v[4]; int sm = 0;
  #pragma unroll
  for (int k = 0; k < 4; ++k) {
    int idx = t * 4 + k;
    v[k] = (idx < nb) ? ghist[idx] : 0;
    sm += v[k];
  }
  temp[t] = sm; __syncthreads();
  int inc = sm;
  for (int off = 1; off < BLK; off <<= 1) {
    int u = (t >= off) ? temp[t - off] : 0; __syncthreads();
    inc += u; temp[t] = inc; __syncthreads();
  }
  int run = inc - sm;
  #pragma unroll
  for (int k = 0; k < 4; ++k) {
    int idx = t * 4 + k;
    if (idx < nb) { base[idx] = run; cursor[idx] = run; }
    run += v[k];
  }
  if (t == BLK - 1) base[nb] = E;
}

// bin edges into per-bucket segments, rec = (src<<8)|(dst&255)
// staged in LDS; flush via slot->bucket u16 map (no binary search)
__global__ void k_bin(const int* __restrict__ src, const int* __restrict__ dst,
                      int* __restrict__ cursor, int* __restrict__ binned,
                      int E, int nb) {
  __shared__ int cb[NBMAX + 1];          // counts -> scanned local base
  __shared__ int cur[NBMAX];
  __shared__ int gofs[NBMAX];            // global ofs -> delta (gofs - base)
  __shared__ int temp[BLK];
  __shared__ int stage[CH];
  __shared__ unsigned short bkt[CH];     // slot -> bucket
  int t = threadIdx.x;
  for (int i = t; i < NBMAX; i += BLK) { cb[i] = 0; cur[i] = 0; }
  __syncthreads();
  long long s0 = (long long)blockIdx.x * CH;
  int c = (int)min((long long)CH, (long long)E - s0);
  // count
  if (c == CH) {
    const int4* d4 = (const int4*)(dst + s0);
    for (int i = t; i < (CH >> 2); i += BLK) {
      int4 v = d4[i];
      atomicAdd(&cb[v.x >> 8], 1); atomicAdd(&cb[v.y >> 8], 1);
      atomicAdd(&cb[v.z >> 8], 1); atomicAdd(&cb[v.w >> 8], 1);
    }
  } else {
    for (int i = t; i < c; i += BLK) atomicAdd(&cb[dst[s0 + i] >> 8], 1);
  }
  __syncthreads();
  // counts to registers
  int v[4];
  #pragma unroll
  for (int k = 0; k < 4; ++k) v[k] = cb[t * 4 + k];
  int sm = v[0] + v[1] + v[2] + v[3];
  temp[t] = sm; __syncthreads();
  int inc = sm;
  for (int off = 1; off < BLK; off <<= 1) {
    int u = (t >= off) ? temp[t - off] : 0; __syncthreads();
    inc += u; temp[t] = inc; __syncthreads();
  }
  // reserve global ranges from register counts
  #pragma unroll
  for (int k = 0; k < 4; ++k) {
    int b = t * 4 + k;
    if (v[k]) gofs[b] = atomicAdd(&cursor[b], v[k]);
  }
  // overwrite cb with scanned local bases
  int run = inc - sm;
  #pragma unroll
  for (int k = 0; k < 4; ++k) { cb[t * 4 + k] = run; run += v[k]; }
  if (t == BLK - 1) cb[NBMAX] = c;
  __syncthreads();
  // delta + slot->bucket map (run fill, no atomics)
  #pragma unroll
  for (int k = 0; k < 4; ++k) {
    int b = t * 4 + k;
    int s_ = cb[b], e_ = cb[b + 1];
    if (e_ > s_) {
      gofs[b] -= s_;
      for (int i = s_; i < e_; ++i) bkt[i] = (unsigned short)b;
    }
  }
  __syncthreads();
  // place into stage
  if (c == CH) {
    const int4* d4 = (const int4*)(dst + s0);
    const int4* s4 = (const int4*)(src + s0);
    for (int i = t; i < (CH >> 2); i += BLK) {
      int4 dv = d4[i]; int4 sv = s4[i];
      int b, r;
      b = dv.x >> 8; r = atomicAdd(&cur[b], 1); stage[cb[b] + r] = (sv.x << 8) | (dv.x & 255);
      b = dv.y >> 8; r = atomicAdd(&cur[b], 1); stage[cb[b] + r] = (sv.y << 8) | (dv.y & 255);
      b = dv.z >> 8; r = atomicAdd(&cur[b], 1); stage[cb[b] + r] = (sv.z << 8) | (dv.z & 255);
      b = dv.w >> 8; r = atomicAdd(&cur[b], 1); stage[cb[b] + r] = (sv.w << 8) | (dv.w & 255);
    }
  } else {
    for (int i = t; i < c; i += BLK) {
      int d = dst[s0 + i];
      int b = d >> 8;
      int r = atomicAdd(&cur[b], 1);
      stage[cb[b] + r] = (src[s0 + i] << 8) | (d & 255);
    }
  }
  __syncthreads();
  // flush: stage order -> contiguous per-run global writes
  for (int i = t; i < c; i += BLK) {
    int b = bkt[i];
    binned[(size_t)i + gofs[b]] = stage[i];
  }
}

// per-bucket counting sort: binned run -> csr (per-node grouped), rowptr, dis
__global__ void k_sortdis(const int* __restrict__ base, const int* __restrict__ binned,
                          int* __restrict__ csr, int* __restrict__ rowptr,
                          float* __restrict__ dis, int n) {
  __shared__ int cnt[256], loff[256], cur[256], temp[BLK];
  int b = blockIdx.x, t = threadIdx.x;
  cnt[t] = 0; cur[t] = 0;
  __syncthreads();
  int s = base[b], e = base[b + 1];
  for (int i = s + t; i < e; i += BLK) atomicAdd(&cnt[binned[i] & 255], 1);
  __syncthreads();
  int v = cnt[t];
  temp[t] = v; __syncthreads();
  int inc = v;
  for (int off = 1; off < BLK; off <<= 1) {
    int u = (t >= off) ? temp[t - off] : 0; __syncthreads();
    inc += u; temp[t] = inc; __syncthreads();
  }
  loff[t] = inc - v;
  int node = b * 256 + t;
  if (node < n) {
    rowptr[node] = s + inc - v;
    dis[node] = rsqrtf((float)(v + 1));   // +1 self-loop
  }
  __syncthreads();
  for (int i = s + t; i < e; i += BLK) {
    int rec = binned[i];
    int L = rec & 255;
    int p = atomicAdd(&cur[L], 1);
    csr[s + loff[L] + p] = rec >> 8;
  }
}

// fused gather + mid layer: y2 = dis*(relu(dis*(acc+y)+b1) @ W2)
// wave-per-node: 64 lanes = 32 edges x 2 float4-halves
__global__ void k_gmid(const int* __restrict__ rowptr, const int* __restrict__ csr,
                       const float* __restrict__ y, float* __restrict__ y2,
                       const float* __restrict__ dis, const float* __restrict__ W2,
                       const float* __restrict__ b1, int n) {
  __shared__ float sW[64], sb[8];
  if (threadIdx.x < 64) sW[threadIdx.x] = W2[threadIdx.x];
  if (threadIdx.x < 8)  sb[threadIdx.x] = b1[threadIdx.x];
  __syncthreads();
  int node = (int)(((long long)blockIdx.x * BLK + threadIdx.x) >> 6);
  if (node >= n) return;
  int lane = threadIdx.x & 63;
  int e = lane & 31, fq = lane >> 5;
  int start = rowptr[node], end = rowptr[node + 1];
  float4 s = make_float4(0.f, 0.f, 0.f, 0.f);
  int k = start + e;
  int sidx = (k < end) ? csr[k] : -1;
  for (int k0 = start; k0 < end; k0 += 32) {
    int nk = k0 + 32 + e;
    int nsidx = (nk < end) ? csr[nk] : -1;
    if (sidx >= 0) {
      const float4 v = *(const float4*)(y + (size_t)sidx * 8 + fq * 4);
      s.x += v.x; s.y += v.y; s.z += v.z; s.w += v.w;
    }
    sidx = nsidx;
  }
  #pragma unroll
  for (int m = 1; m <= 16; m <<= 1) {
    s.x += __shfl_xor(s.x, m);
    s.y += __shfl_xor(s.y, m);
    s.z += __shfl_xor(s.z, m);
    s.w += __shfl_xor(s.w, m);
  }
  // lanes<32 hold acc[0:4]; fetch acc[4:8] from upper half
  float h0 = __shfl(s.x, lane | 32);
  float h1 = __shfl(s.y, lane | 32);
  float h2 = __shfl(s.z, lane | 32);
  float h3 = __shfl(s.w, lane | 32);
  int j = lane;   // only j<8 meaningful
  float accj = (j == 0) ? s.x : (j == 1) ? s.y : (j == 2) ? s.z : (j == 3) ? s.w
             : (j == 4) ? h0  : (j == 5) ? h1  : (j == 6) ? h2  : h3;
  float dsv = dis[node];
  float yj = (lane < 8) ? y[(size_t)node * 8 + lane] : 0.f;
  float bj = (lane < 8) ? sb[lane] : 0.f;
  float hv = fmaxf(fmaf(dsv, accj + yj, bj), 0.f);
  float o = 0.f;
  #pragma unroll
  for (int kk = 0; kk < 8; ++kk) {
    float hk = __shfl(hv, kk);
    if (lane < 8) o = fmaf(hk, sW[kk * 8 + lane], o);
  }
  if (lane < 8) y2[(size_t)node * 8 + lane] = dsv * o;
}

// fused gather + final: zn[node] = relu(dis*(acc+y2)+b2) . Wl  (no atomics)
__global__ void k_gfin(const int* __restrict__ rowptr, const int* __restrict__ csr,
                       const float* __restrict__ y2, const float* __restrict__ dis,
                       const float* __restrict__ b2, const float* __restrict__ Wl,
                       float* __restrict__ zn, int n) {
  __shared__ float sb[8], sw[8];
  if (threadIdx.x < 8) { sb[threadIdx.x] = b2[threadIdx.x]; sw[threadIdx.x] = Wl[threadIdx.x]; }
  __syncthreads();
  int node = (int)(((long long)blockIdx.x * BLK + threadIdx.x) >> 6);
  if (node >= n) return;
  int lane = threadIdx.x & 63;
  int e = lane & 31, fq = lane >> 5;
  int start = rowptr[node], end = rowptr[node + 1];
  float4 s = make_float4(0.f, 0.f, 0.f, 0.f);
  int k = start + e;
  int sidx = (k < end) ? csr[k] : -1;
  for (int k0 = start; k0 < end; k0 += 32) {
    int nk = k0 + 32 + e;
    int nsidx = (nk < end) ? csr[nk] : -1;
    if (sidx >= 0) {
      const float4 v = *(const float4*)(y2 + (size_t)sidx * 8 + fq * 4);
      s.x += v.x; s.y += v.y; s.z += v.z; s.w += v.w;
    }
    sidx = nsidx;
  }
  #pragma unroll
  for (int m = 1; m <= 16; m <<= 1) {
    s.x += __shfl_xor(s.x, m);
    s.y += __shfl_xor(s.y, m);
    s.z += __shfl_xor(s.z, m);
    s.w += __shfl_xor(s.w, m);
  }
  float h0 = __shfl(s.x, lane | 32);
  float h1 = __shfl(s.y, lane | 32);
  float h2 = __shfl(s.z, lane | 32);
  float h3 = __shfl(s.w, lane | 32);
  int j = lane;
  float accj = (j == 0) ? s.x : (j == 1) ? s.y : (j == 2) ? s.z : (j == 3) ? s.w
             : (j == 4) ? h0  : (j == 5) ? h1  : (j == 6) ? h2  : h3;
  float dsv = dis[node];
  float yj = (lane < 8) ? y2[(size_t)node * 8 + lane] : 0.f;
  float bj = (lane < 8) ? sb[lane] : 0.f;
  float wj = (lane < 8) ? sw[lane] : 0.f;
  float p = fmaxf(fmaf(dsv, accj + yj, bj), 0.f) * wj;
  p += __shfl_xor(p, 1);
  p += __shfl_xor(p, 2);
  p += __shfl_xor(p, 4);
  if (lane == 0) zn[node] = p;
}

// pool zn -> zacc with sorted-batch wave aggregation (~1 atomic per 64 nodes)
__global__ void k_pool(const float* __restrict__ zn, const int* __restrict__ batch,
                       float* __restrict__ zacc, int n) {
  int i = blockIdx.x * BLK + threadIdx.x;
  float s = 0.f;
  int g = -1;
  if (i < n) { s = zn[i]; g = batch[i]; }
  int g0 = __shfl(g, 0);
  bool uni = __all(g == g0);
  if (uni) {
    #pragma unroll
    for (int off = 32; off > 0; off >>= 1) s += __shfl_down(s, off);
    if ((threadIdx.x & 63) == 0 && g0 >= 0) unsafeAtomicAdd(&zacc[g0], s);
  } else if (i < n) {
    unsafeAtomicAdd(&zacc[g], s);
  }
}

// ================= tier-2 fallback (R5 proven) =================

__global__ void k_degdis(const int* __restrict__ base, const int* __restrict__ binned,
                         float* __restrict__ dis, int n) {
  __shared__ int deg[256];
  int b = blockIdx.x, t = threadIdx.x;
  deg[t] = 1;
  __syncthreads();
  int s = base[b], e = base[b + 1];
  for (int i = s + t; i < e; i += BLK) atomicAdd(&deg[binned[i] & 255], 1);
  __syncthreads();
  int node = b * 256 + t;
  if (node < n) dis[node] = rsqrtf((float)deg[t]);
}

__global__ void k_acc(const int* __restrict__ base, const int* __restrict__ binned,
                      const float* __restrict__ y, float* __restrict__ acc, int n) {
  __shared__ float fa[2048];
  int b = blockIdx.x, t = threadIdx.x;
  for (int i = t; i < 2048; i += BLK) fa[i] = 0.f;
  __syncthreads();
  int s = base[b], e = base[b + 1];
  int j = t & 7;
  for (int i = s + (t >> 3); i < e; i += 32) {
    int rec = binned[i];
    atomicAdd(&fa[(rec & 255) * 8 + j], y[(size_t)(rec >> 8) * 8 + j]);
  }
  __syncthreads();
  int node0 = b * 256;
  int lim = (n - node0 < 256 ? n - node0 : 256) * 8;
  for (int i = t; i < lim; i += BLK) acc[(size_t)node0 * 8 + i] = fa[i];
}

// ================= dense stages =================

__global__ void k_y1n(const float* __restrict__ x, const float* __restrict__ W1,
                      const float* __restrict__ dis, float* __restrict__ y, int n) {
  __shared__ float sW[128];
  if (threadIdx.x < 128) sW[threadIdx.x] = W1[threadIdx.x];
  __syncthreads();
  int i = blockIdx.x * BLK + threadIdx.x;
  if (i >= n) return;
  const float4* xp = (const float4*)(x + (size_t)i * 16);
  float4 a = xp[0], bb = xp[1], cc = xp[2], d4 = xp[3];
  float xv[16] = {a.x,a.y,a.z,a.w, bb.x,bb.y,bb.z,bb.w,
                  cc.x,cc.y,cc.z,cc.w, d4.x,d4.y,d4.z,d4.w};
  float ds = dis[i];
  float o[8];
  #pragma unroll
  for (int jj = 0; jj < 8; ++jj) {
    float s = 0.f;
    #pragma unroll
    for (int k = 0; k < 16; ++k) s = fmaf(xv[k], sW[k*8 + jj], s);
    o[jj] = ds * s;
  }
  float4* yp = (float4*)(y + (size_t)i * 8);
  yp[0] = make_float4(o[0], o[1], o[2], o[3]);
  yp[1] = make_float4(o[4], o[5], o[6], o[7]);
}

__global__ void k_mid(const float* __restrict__ dis, float* __restrict__ y,
                      float* __restrict__ acc, const float* __restrict__ W2,
                      const float* __restrict__ b1, int n, int zero_acc) {
  __shared__ float sW[64];
  __shared__ float sb[8];
  if (threadIdx.x < 64) sW[threadIdx.x] = W2[threadIdx.x];
  if (threadIdx.x < 8)  sb[threadIdx.x] = b1[threadIdx.x];
  __syncthreads();
  int i = blockIdx.x * BLK + threadIdx.x;
  if (i >= n) return;
  float d = dis[i];
  float4* yp = (float4*)(y + (size_t)i * 8);
  float4* ap = (float4*)(acc + (size_t)i * 8);
  float4 y0 = yp[0], y1v = yp[1], a0 = ap[0], a1 = ap[1];
  float yy[8] = {y0.x,y0.y,y0.z,y0.w, y1v.x,y1v.y,y1v.z,y1v.w};
  float aa[8] = {a0.x,a0.y,a0.z,a0.w, a1.x,a1.y,a1.z,a1.w};
  float hv[8];
  #pragma unroll
  for (int jj = 0; jj < 8; ++jj) hv[jj] = fmaxf(fmaf(d, yy[jj] + aa[jj], sb[jj]), 0.f);
  float o[8];
  #pragma unroll
  for (int jj = 0; jj < 8; ++jj) {
    float s = 0.f;
    #pragma unroll
    for (int k = 0; k < 8; ++k) s = fmaf(hv[k], sW[k*8 + jj], s);
    o[jj] = d * s;
  }
  yp[0] = make_float4(o[0], o[1], o[2], o[3]);
  yp[1] = make_float4(o[4], o[5], o[6], o[7]);
  if (zero_acc) {
    ap[0] = make_float4(0.f, 0.f, 0.f, 0.f);
    ap[1] = make_float4(0.f, 0.f, 0.f, 0.f);
  }
}

__global__ void k_final(const float* __restrict__ dis, const float* __restrict__ y,
                        const float* __restrict__ acc, const float* __restrict__ b2,
                        const float* __restrict__ Wl, const int* __restrict__ batch,
                        float* __restrict__ zacc, int n) {
  __shared__ float sb[8], sw[8];
  if (threadIdx.x < 8) { sb[threadIdx.x] = b2[threadIdx.x]; sw[threadIdx.x] = Wl[threadIdx.x]; }
  __syncthreads();
  int i = blockIdx.x * BLK + threadIdx.x;
  float s = 0.f;
  int g = -1;
  if (i < n) {
    float d = dis[i];
    const float4* yp = (const float4*)(y + (size_t)i * 8);
    const float4* ap = (const float4*)(acc + (size_t)i * 8);
    float4 y0 = yp[0], y1v = yp[1], a0 = ap[0], a1 = ap[1];
    float yy[8] = {y0.x,y0.y,y0.z,y0.w, y1v.x,y1v.y,y1v.z,y1v.w};
    float aa[8] = {a0.x,a0.y,a0.z,a0.w, a1.x,a1.y,a1.z,a1.w};
    #pragma unroll
    for (int jj = 0; jj < 8; ++jj) {
      float h = fmaxf(fmaf(d, yy[jj] + aa[jj], sb[jj]), 0.f);
      s = fmaf(h, sw[jj], s);
    }
    g = batch[i];
  }
  int g0 = __shfl(g, 0);
  bool uni = __all(g == g0);
  if (uni) {
    #pragma unroll
    for (int off = 32; off > 0; off >>= 1) s += __shfl_down(s, off);
    if ((threadIdx.x & 63) == 0 && g0 >= 0) unsafeAtomicAdd(&zacc[g0], s);
  } else if (i < n) {
    unsafeAtomicAdd(&zacc[g], s);
  }
}

__global__ void k_out(const float* __restrict__ zacc, const float* __restrict__ bl,
                      float* __restrict__ out, int ng) {
  int i = blockIdx.x * BLK + threadIdx.x;
  if (i < ng) {
    float z = zacc[i] + bl[0];
    float r;
    if (z >= 0.f) { r = 1.f / (1.f + expf(-z)); }
    else          { float e = expf(z); r = e / (1.f + e); }
    out[i] = r;
  }
}

// ================= tier-3 fallback (R2 proven) =================

__global__ void k_init(int* __restrict__ deg, float* __restrict__ acc,
                       float* __restrict__ zacc, int n, int accn, int ng) {
  int jj = blockIdx.x * BLK + threadIdx.x;
  if (jj < accn) acc[jj] = 0.f;
  if (jj < n) deg[jj] = 1;
  if (jj < ng) zacc[jj] = 0.f;
}

__global__ void k_deg(const int* __restrict__ dst, int* __restrict__ deg, int E) {
  int i = blockIdx.x * BLK + threadIdx.x;
  if (i < E) atomicAdd(&deg[dst[i]], 1);
}

__global__ void k_y1(const float* __restrict__ x, const float* __restrict__ W1,
                     int* __restrict__ degdis, float* __restrict__ y, int n) {
  __shared__ float sW[128];
  if (threadIdx.x < 128) sW[threadIdx.x] = W1[threadIdx.x];
  __syncthreads();
  int i = blockIdx.x * BLK + threadIdx.x;
  if (i >= n) return;
  const float4* xp = (const float4*)(x + (size_t)i * 16);
  float4 a = xp[0], bb = xp[1], cc = xp[2], d4 = xp[3];
  float xv[16] = {a.x,a.y,a.z,a.w, bb.x,bb.y,bb.z,bb.w,
                  cc.x,cc.y,cc.z,cc.w, d4.x,d4.y,d4.z,d4.w};
  float ds = rsqrtf((float)degdis[i]);
  float o[8];
  #pragma unroll
  for (int jj = 0; jj < 8; ++jj) {
    float s = 0.f;
    #pragma unroll
    for (int k = 0; k < 16; ++k) s = fmaf(xv[k], sW[k*8 + jj], s);
    o[jj] = ds * s;
  }
  ((float*)degdis)[i] = ds;
  float4* yp = (float4*)(y + (size_t)i * 8);
  yp[0] = make_float4(o[0], o[1], o[2], o[3]);
  yp[1] = make_float4(o[4], o[5], o[6], o[7]);
}

__global__ void k_scatter(const int* __restrict__ src, const int* __restrict__ dst,
                          const float* __restrict__ y, float* __restrict__ acc,
                          long long total) {
  long long t = (long long)blockIdx.x * BLK + threadIdx.x;
  if (t >= total) return;
  int e = (int)(t >> 3);
  int h = (int)(t & 7);
  int s = src[e], d = dst[e];
  unsafeAtomicAdd(&acc[(size_t)d * 8 + h], y[(size_t)s * 8 + h]);
}

// ================= host =================

static inline size_t alignup(size_t v) { return (v + 255) & ~(size_t)255; }

extern "C" void kernel_launch(void* const* d_in, const int* in_sizes, int n_in,
                              void* d_out, int out_size, void* d_ws, size_t ws_size,
                              hipStream_t stream) {
  const float* x   = (const float*)d_in[0];
  const int*   ei  = (const int*)  d_in[1];
  const int*   bat = (const int*)  d_in[2];
  const float* W1  = (const float*)d_in[3];
  const float* b1  = (const float*)d_in[4];
  const float* W2  = (const float*)d_in[5];
  const float* b2  = (const float*)d_in[6];
  const float* Wl  = (const float*)d_in[7];
  const float* bl  = (const float*)d_in[8];
  float* out = (float*)d_out;

  int n  = in_sizes[0] / 16;   // 250000
  int E  = in_sizes[1] / 2;    // 8000000
  int ng = out_size;           // 512

  const int* src = ei;
  const int* dst = ei + E;

  int nb = (n + 255) >> 8;     // 977

  char* wsb = (char*)d_ws;
  size_t offY  = alignup((size_t)n * 4);                  // dis
  size_t offA  = offY + alignup((size_t)n * 8 * 4);       // y
  size_t offZ  = offA + alignup((size_t)n * 8 * 4);       // acc / y2
  size_t offZn = offZ + alignup((size_t)ng * 4);          // zacc
  size_t offH  = offZn + alignup((size_t)n * 4);          // zn
  size_t offB  = offH + alignup((size_t)NBMAX * 4);       // ghist
  size_t offCu = offB + alignup((size_t)(NBMAX + 1) * 4); // base
  size_t offBn = offCu + alignup((size_t)NBMAX * 4);      // cursor
  size_t offRp = offBn + alignup((size_t)E * 4);          // binned
  size_t offCs = offRp + alignup(((size_t)n + 1) * 4);    // rowptr
  size_t need1 = offCs + alignup((size_t)E * 4);          // csr
  size_t need2 = offRp;                                   // tier-2: through binned

  float* dis    = (float*)wsb;
  int*   deg    = (int*)wsb;
  float* y      = (float*)(wsb + offY);
  float* acc    = (float*)(wsb + offA);   // y2 alias in tier-1
  float* zacc   = (float*)(wsb + offZ);
  float* zn     = (float*)(wsb + offZn);
  int*   ghist  = (int*)(wsb + offH);
  int*   base   = (int*)(wsb + offB);
  int*   cursor = (int*)(wsb + offCu);
  int*   binned = (int*)(wsb + offBn);
  int*   rowptr = (int*)(wsb + offRp);
  int*   csr    = (int*)(wsb + offCs);

  int gN = (n + BLK - 1) / BLK;
  int gG = (ng + BLK - 1) / BLK;
  int gW = (int)(((long long)n * 64 + BLK - 1) / BLK);   // wave-per-node

  bool ok_bin = (nb <= NBMAX) && (n < (1 << 23));
  bool tier1 = ok_bin && (ws_size >= need1);
  bool tier2 = ok_bin && (ws_size >= need2);

  if (tier1 || tier2) {
    int histChunk = 8192;
    int gHist = (int)(((long long)E + histChunk - 1) / histChunk);
    int gBin  = (int)(((long long)E + CH - 1) / CH);
    int gI0   = (NBMAX > ng ? NBMAX : ng) / BLK + 1;
    k_init0 <<<gI0, BLK, 0, stream>>>(ghist, zacc, rowptr, NBMAX, ng, n, E, tier1 ? 1 : 0);
    k_hist  <<<gHist, BLK, 0, stream>>>(dst, ghist, E, nb, histChunk);
    k_scan  <<<1, BLK, 0, stream>>>(ghist, base, cursor, nb, E);
    k_bin   <<<gBin, BLK, 0, stream>>>(src, dst, cursor, binned, E, nb);
    if (tier1) {
      k_sortdis<<<nb, BLK, 0, stream>>>(base, binned, csr, rowptr, dis, n);
      k_y1n   <<<gN, BLK, 0, stream>>>(x, W1, dis, y, n);
      k_gmid  <<<gW, BLK, 0, stream>>>(rowptr, csr, y, acc, dis, W2, b1, n);
      k_gfin  <<<gW, BLK, 0, stream>>>(rowptr, csr, acc, dis, b2, Wl, zn, n);
      k_pool  <<<gN, BLK, 0, stream>>>(zn, bat, zacc, n);
    } else {
      k_degdis<<<nb, BLK, 0, stream>>>(base, binned, dis, n);
      k_y1n   <<<gN, BLK, 0, stream>>>(x, W1, dis, y, n);
      k_acc   <<<nb, BLK, 0, stream>>>(base, binned, y, acc, n);
      k_mid   <<<gN, BLK, 0, stream>>>(dis, y, acc, W2, b1, n, 0);
      k_acc   <<<nb, BLK, 0, stream>>>(base, binned, y, acc, n);
      k_final <<<gN, BLK, 0, stream>>>(dis, y, acc, b2, Wl, bat, zacc, n);
    }
  } else {
    int accn = n * 8;
    long long tot = (long long)E * 8;
    int gInit = (accn + BLK - 1) / BLK;
    int gE    = (E + BLK - 1) / BLK;
    int gS    = (int)((tot + BLK - 1) / BLK);
    k_init   <<<gInit, BLK, 0, stream>>>(deg, acc, zacc, n, accn, ng);
    k_deg    <<<gE, BLK, 0, stream>>>(dst, deg, E);
    k_y1     <<<gN, BLK, 0, stream>>>(x, W1, deg, y, n);
    k_scatter<<<gS, BLK, 0, stream>>>(src, dst, y, acc, tot);
    k_mid    <<<gN, BLK, 0, stream>>>(dis, y, acc, W2, b1, n, 1);
    k_scatter<<<gS, BLK, 0, stream>>>(src, dst, y, acc, tot);
    k_final  <<<gN, BLK, 0, stream>>>(dis, y, acc, b2, Wl, bat, zacc, n);
  }
  k_out<<<gG, BLK, 0, stream>>>(zacc, bl, out, ng);
}

// Round 12
// 459.888 us; speedup vs baseline: 2.5986x; 1.1924x over previous
//
#include <hip/hip_runtime.h>
#include <math.h>

#define BLK 256
#define CH 4096          // edges per k_bin block (staged)
#define NBMAX 1024       // max buckets (256 nodes each)

typedef unsigned short ushortT;

__device__ __forceinline__ float bf2f(unsigned short u) {
  return __uint_as_float(((unsigned int)u) << 16);
}
__device__ __forceinline__ unsigned short f2bf(float f) {
  unsigned int u = __float_as_uint(f);
  return (unsigned short)((u + 0x7fffu + ((u >> 16) & 1u)) >> 16);
}

// ================= binned + CSR path =================

__global__ void k_init0(int* __restrict__ ghist, float* __restrict__ zacc,
                        int* __restrict__ rowptr, int nb, int ng, int n, int E,
                        int primary) {
  int i = blockIdx.x * BLK + threadIdx.x;
  if (i < nb) ghist[i] = 0;
  if (i < ng) zacc[i] = 0.f;
  if (primary && i == 0) rowptr[n] = E;
}

// per-bucket histogram of dst>>8 (int4 fast path)
__global__ void k_hist(const int* __restrict__ dst, int* __restrict__ ghist,
                       int E, int nb, int chunk) {
  __shared__ int h[NBMAX];
  for (int i = threadIdx.x; i < NBMAX; i += BLK) h[i] = 0;
  __syncthreads();
  long long s0 = (long long)blockIdx.x * chunk;
  int c = (int)min((long long)chunk, (long long)E - s0);
  if (c == chunk && (chunk & 3) == 0) {
    const int4* d4 = (const int4*)(dst + s0);
    int m = chunk >> 2;
    for (int i = threadIdx.x; i < m; i += BLK) {
      int4 v = d4[i];
      atomicAdd(&h[v.x >> 8], 1); atomicAdd(&h[v.y >> 8], 1);
      atomicAdd(&h[v.z >> 8], 1); atomicAdd(&h[v.w >> 8], 1);
    }
  } else {
    for (int i = threadIdx.x; i < c; i += BLK)
      atomicAdd(&h[dst[s0 + i] >> 8], 1);
  }
  __syncthreads();
  for (int b = threadIdx.x; b < nb; b += BLK)
    if (h[b]) atomicAdd(&ghist[b], h[b]);
}

__global__ void k_scan(const int* __restrict__ ghist, int* __restrict__ base,
                       int* __restrict__ cursor, int nb, int E) {
  __shared__ int temp[BLK];
  int t = threadIdx.x;
  int v[4]; int sm = 0;
  #pragma unroll
  for (int k = 0; k < 4; ++k) {
    int idx = t * 4 + k;
    v[k] = (idx < nb) ? ghist[idx] : 0;
    sm += v[k];
  }
  temp[t] = sm; __syncthreads();
  int inc = sm;
  for (int off = 1; off < BLK; off <<= 1) {
    int u = (t >= off) ? temp[t - off] : 0; __syncthreads();
    inc += u; temp[t] = inc; __syncthreads();
  }
  int run = inc - sm;
  #pragma unroll
  for (int k = 0; k < 4; ++k) {
    int idx = t * 4 + k;
    if (idx < nb) { base[idx] = run; cursor[idx] = run; }
    run += v[k];
  }
  if (t == BLK - 1) base[nb] = E;
}

// bin edges (R9-proven staged + binary-search flush), rec = (src<<8)|(dst&255)
__global__ void k_bin(const int* __restrict__ src, const int* __restrict__ dst,
                      int* __restrict__ cursor, int* __restrict__ binned,
                      int E, int nb) {
  __shared__ int cnt[NBMAX], cur[NBMAX], gofs[NBMAX], baseA[NBMAX + 1], temp[BLK];
  __shared__ int stage[CH];
  int t = threadIdx.x;
  for (int i = t; i < NBMAX; i += BLK) { cnt[i] = 0; cur[i] = 0; }
  __syncthreads();
  long long s0 = (long long)blockIdx.x * CH;
  int c = (int)min((long long)CH, (long long)E - s0);
  for (int i = t; i < c; i += BLK) atomicAdd(&cnt[dst[s0 + i] >> 8], 1);
  __syncthreads();
  int v[4], sm = 0;
  #pragma unroll
  for (int k = 0; k < 4; ++k) { v[k] = cnt[t * 4 + k]; sm += v[k]; }
  temp[t] = sm; __syncthreads();
  int inc = sm;
  for (int off = 1; off < BLK; off <<= 1) {
    int u = (t >= off) ? temp[t - off] : 0; __syncthreads();
    inc += u; temp[t] = inc; __syncthreads();
  }
  int run = inc - sm;
  #pragma unroll
  for (int k = 0; k < 4; ++k) { baseA[t * 4 + k] = run; run += v[k]; }
  if (t == BLK - 1) baseA[NBMAX] = c;
  __syncthreads();
  for (int b = t; b < nb; b += BLK)
    if (cnt[b]) gofs[b] = atomicAdd(&cursor[b], cnt[b]);
  __syncthreads();
  for (int i = t; i < c; i += BLK) {
    int d = dst[s0 + i];
    int b = d >> 8;
    int r = atomicAdd(&cur[b], 1);
    stage[baseA[b] + r] = (src[s0 + i] << 8) | (d & 255);
  }
  __syncthreads();
  for (int i = t; i < c; i += BLK) {
    int lo = 0, hi = nb;
    while (hi - lo > 1) { int m = (lo + hi) >> 1; if (baseA[m] <= i) lo = m; else hi = m; }
    binned[(size_t)gofs[lo] + (i - baseA[lo])] = stage[i];
  }
}

// per-bucket counting sort: binned run -> csr (per-node grouped), rowptr, dis
__global__ void k_sortdis(const int* __restrict__ base, const int* __restrict__ binned,
                          int* __restrict__ csr, int* __restrict__ rowptr,
                          float* __restrict__ dis, int n) {
  __shared__ int cnt[256], loff[256], cur[256], temp[BLK];
  int b = blockIdx.x, t = threadIdx.x;
  cnt[t] = 0; cur[t] = 0;
  __syncthreads();
  int s = base[b], e = base[b + 1];
  for (int i = s + t; i < e; i += BLK) atomicAdd(&cnt[binned[i] & 255], 1);
  __syncthreads();
  int v = cnt[t];
  temp[t] = v; __syncthreads();
  int inc = v;
  for (int off = 1; off < BLK; off <<= 1) {
    int u = (t >= off) ? temp[t - off] : 0; __syncthreads();
    inc += u; temp[t] = inc; __syncthreads();
  }
  loff[t] = inc - v;
  int node = b * 256 + t;
  if (node < n) {
    rowptr[node] = s + inc - v;
    dis[node] = rsqrtf((float)(v + 1));   // +1 self-loop
  }
  __syncthreads();
  for (int i = s + t; i < e; i += BLK) {
    int rec = binned[i];
    int L = rec & 255;
    int p = atomicAdd(&cur[L], 1);
    csr[s + loff[L] + p] = rec >> 8;
  }
}

// y1 (bf16): y = dis * (x @ W1)
__global__ void k_y1b(const float* __restrict__ x, const float* __restrict__ W1,
                      const float* __restrict__ dis, ushortT* __restrict__ ybf, int n) {
  __shared__ float sW[128];
  if (threadIdx.x < 128) sW[threadIdx.x] = W1[threadIdx.x];
  __syncthreads();
  int i = blockIdx.x * BLK + threadIdx.x;
  if (i >= n) return;
  const float4* xp = (const float4*)(x + (size_t)i * 16);
  float4 a = xp[0], bb = xp[1], cc = xp[2], d4 = xp[3];
  float xv[16] = {a.x,a.y,a.z,a.w, bb.x,bb.y,bb.z,bb.w,
                  cc.x,cc.y,cc.z,cc.w, d4.x,d4.y,d4.z,d4.w};
  float ds = dis[i];
  float o[8];
  #pragma unroll
  for (int jj = 0; jj < 8; ++jj) {
    float s = 0.f;
    #pragma unroll
    for (int k = 0; k < 16; ++k) s = fmaf(xv[k], sW[k*8 + jj], s);
    o[jj] = ds * s;
  }
  uint4 p;
  p.x = (unsigned int)f2bf(o[0]) | ((unsigned int)f2bf(o[1]) << 16);
  p.y = (unsigned int)f2bf(o[2]) | ((unsigned int)f2bf(o[3]) << 16);
  p.z = (unsigned int)f2bf(o[4]) | ((unsigned int)f2bf(o[5]) << 16);
  p.w = (unsigned int)f2bf(o[6]) | ((unsigned int)f2bf(o[7]) << 16);
  *(uint4*)(ybf + (size_t)i * 8) = p;
}

// fused gather + mid (bf16 in/out): y2 = dis*(relu(dis*(acc+y)+b1) @ W2)
__global__ void k_gmid(const int* __restrict__ rowptr, const int* __restrict__ csr,
                       const ushortT* __restrict__ ybf, ushortT* __restrict__ y2bf,
                       const float* __restrict__ dis, const float* __restrict__ W2,
                       const float* __restrict__ b1, int n) {
  __shared__ float sW[64], sb[8];
  if (threadIdx.x < 64) sW[threadIdx.x] = W2[threadIdx.x];
  if (threadIdx.x < 8)  sb[threadIdx.x] = b1[threadIdx.x];
  __syncthreads();
  int node = (int)(((long long)blockIdx.x * BLK + threadIdx.x) >> 6);
  if (node >= n) return;
  int lane = threadIdx.x & 63;
  int e = lane & 31, fq = lane >> 5;
  int start = rowptr[node], end = rowptr[node + 1];
  float4 s = make_float4(0.f, 0.f, 0.f, 0.f);
  int k = start + e;
  int sidx = (k < end) ? csr[k] : -1;
  for (int k0 = start; k0 < end; k0 += 32) {
    int nk = k0 + 32 + e;
    int nsidx = (nk < end) ? csr[nk] : -1;
    if (sidx >= 0) {
      const uint2 v = *(const uint2*)(ybf + (size_t)sidx * 8 + fq * 4);
      s.x += __uint_as_float(v.x << 16);
      s.y += __uint_as_float(v.x & 0xFFFF0000u);
      s.z += __uint_as_float(v.y << 16);
      s.w += __uint_as_float(v.y & 0xFFFF0000u);
    }
    sidx = nsidx;
  }
  #pragma unroll
  for (int m = 1; m <= 16; m <<= 1) {
    s.x += __shfl_xor(s.x, m);
    s.y += __shfl_xor(s.y, m);
    s.z += __shfl_xor(s.z, m);
    s.w += __shfl_xor(s.w, m);
  }
  float h0 = __shfl(s.x, lane | 32);
  float h1 = __shfl(s.y, lane | 32);
  float h2 = __shfl(s.z, lane | 32);
  float h3 = __shfl(s.w, lane | 32);
  int j = lane;
  float accj = (j == 0) ? s.x : (j == 1) ? s.y : (j == 2) ? s.z : (j == 3) ? s.w
             : (j == 4) ? h0  : (j == 5) ? h1  : (j == 6) ? h2  : h3;
  float dsv = dis[node];
  float yj = (lane < 8) ? bf2f(ybf[(size_t)node * 8 + lane]) : 0.f;
  float bj = (lane < 8) ? sb[lane] : 0.f;
  float hv = fmaxf(fmaf(dsv, accj + yj, bj), 0.f);
  float o = 0.f;
  #pragma unroll
  for (int kk = 0; kk < 8; ++kk) {
    float hk = __shfl(hv, kk);
    if (lane < 8) o = fmaf(hk, sW[kk * 8 + lane], o);
  }
  if (lane < 8) y2bf[(size_t)node * 8 + lane] = f2bf(dsv * o);
}

// fused gather + final (bf16 in): zn[node] = relu(dis*(acc+y2)+b2) . Wl
__global__ void k_gfin(const int* __restrict__ rowptr, const int* __restrict__ csr,
                       const ushortT* __restrict__ y2bf, const float* __restrict__ dis,
                       const float* __restrict__ b2, const float* __restrict__ Wl,
                       float* __restrict__ zn, int n) {
  __shared__ float sb[8], sw[8];
  if (threadIdx.x < 8) { sb[threadIdx.x] = b2[threadIdx.x]; sw[threadIdx.x] = Wl[threadIdx.x]; }
  __syncthreads();
  int node = (int)(((long long)blockIdx.x * BLK + threadIdx.x) >> 6);
  if (node >= n) return;
  int lane = threadIdx.x & 63;
  int e = lane & 31, fq = lane >> 5;
  int start = rowptr[node], end = rowptr[node + 1];
  float4 s = make_float4(0.f, 0.f, 0.f, 0.f);
  int k = start + e;
  int sidx = (k < end) ? csr[k] : -1;
  for (int k0 = start; k0 < end; k0 += 32) {
    int nk = k0 + 32 + e;
    int nsidx = (nk < end) ? csr[nk] : -1;
    if (sidx >= 0) {
      const uint2 v = *(const uint2*)(y2bf + (size_t)sidx * 8 + fq * 4);
      s.x += __uint_as_float(v.x << 16);
      s.y += __uint_as_float(v.x & 0xFFFF0000u);
      s.z += __uint_as_float(v.y << 16);
      s.w += __uint_as_float(v.y & 0xFFFF0000u);
    }
    sidx = nsidx;
  }
  #pragma unroll
  for (int m = 1; m <= 16; m <<= 1) {
    s.x += __shfl_xor(s.x, m);
    s.y += __shfl_xor(s.y, m);
    s.z += __shfl_xor(s.z, m);
    s.w += __shfl_xor(s.w, m);
  }
  float h0 = __shfl(s.x, lane | 32);
  float h1 = __shfl(s.y, lane | 32);
  float h2 = __shfl(s.z, lane | 32);
  float h3 = __shfl(s.w, lane | 32);
  int j = lane;
  float accj = (j == 0) ? s.x : (j == 1) ? s.y : (j == 2) ? s.z : (j == 3) ? s.w
             : (j == 4) ? h0  : (j == 5) ? h1  : (j == 6) ? h2  : h3;
  float dsv = dis[node];
  float yj = (lane < 8) ? bf2f(y2bf[(size_t)node * 8 + lane]) : 0.f;
  float bj = (lane < 8) ? sb[lane] : 0.f;
  float wj = (lane < 8) ? sw[lane] : 0.f;
  float p = fmaxf(fmaf(dsv, accj + yj, bj), 0.f) * wj;
  p += __shfl_xor(p, 1);
  p += __shfl_xor(p, 2);
  p += __shfl_xor(p, 4);
  if (lane == 0) zn[node] = p;
}

// pool zn -> zacc with sorted-batch wave aggregation (~1 atomic per 64 nodes)
__global__ void k_pool(const float* __restrict__ zn, const int* __restrict__ batch,
                       float* __restrict__ zacc, int n) {
  int i = blockIdx.x * BLK + threadIdx.x;
  float s = 0.f;
  int g = -1;
  if (i < n) { s = zn[i]; g = batch[i]; }
  int g0 = __shfl(g, 0);
  bool uni = __all(g == g0);
  if (uni) {
    #pragma unroll
    for (int off = 32; off > 0; off >>= 1) s += __shfl_down(s, off);
    if ((threadIdx.x & 63) == 0 && g0 >= 0) unsafeAtomicAdd(&zacc[g0], s);
  } else if (i < n) {
    unsafeAtomicAdd(&zacc[g], s);
  }
}

__global__ void k_out(const float* __restrict__ zacc, const float* __restrict__ bl,
                      float* __restrict__ out, int ng) {
  int i = blockIdx.x * BLK + threadIdx.x;
  if (i < ng) {
    float z = zacc[i] + bl[0];
    float r;
    if (z >= 0.f) { r = 1.f / (1.f + expf(-z)); }
    else          { float e = expf(z); r = e / (1.f + e); }
    out[i] = r;
  }
}

// ================= tier-3 fallback (R2 proven) =================

__global__ void k_init(int* __restrict__ deg, float* __restrict__ acc,
                       float* __restrict__ zacc, int n, int accn, int ng) {
  int jj = blockIdx.x * BLK + threadIdx.x;
  if (jj < accn) acc[jj] = 0.f;
  if (jj < n) deg[jj] = 1;
  if (jj < ng) zacc[jj] = 0.f;
}

__global__ void k_deg(const int* __restrict__ dst, int* __restrict__ deg, int E) {
  int i = blockIdx.x * BLK + threadIdx.x;
  if (i < E) atomicAdd(&deg[dst[i]], 1);
}

__global__ void k_y1(const float* __restrict__ x, const float* __restrict__ W1,
                     int* __restrict__ degdis, float* __restrict__ y, int n) {
  __shared__ float sW[128];
  if (threadIdx.x < 128) sW[threadIdx.x] = W1[threadIdx.x];
  __syncthreads();
  int i = blockIdx.x * BLK + threadIdx.x;
  if (i >= n) return;
  const float4* xp = (const float4*)(x + (size_t)i * 16);
  float4 a = xp[0], bb = xp[1], cc = xp[2], d4 = xp[3];
  float xv[16] = {a.x,a.y,a.z,a.w, bb.x,bb.y,bb.z,bb.w,
                  cc.x,cc.y,cc.z,cc.w, d4.x,d4.y,d4.z,d4.w};
  float ds = rsqrtf((float)degdis[i]);
  float o[8];
  #pragma unroll
  for (int jj = 0; jj < 8; ++jj) {
    float s = 0.f;
    #pragma unroll
    for (int k = 0; k < 16; ++k) s = fmaf(xv[k], sW[k*8 + jj], s);
    o[jj] = ds * s;
  }
  ((float*)degdis)[i] = ds;
  float4* yp = (float4*)(y + (size_t)i * 8);
  yp[0] = make_float4(o[0], o[1], o[2], o[3]);
  yp[1] = make_float4(o[4], o[5], o[6], o[7]);
}

__global__ void k_scatter(const int* __restrict__ src, const int* __restrict__ dst,
                          const float* __restrict__ y, float* __restrict__ acc,
                          long long total) {
  long long t = (long long)blockIdx.x * BLK + threadIdx.x;
  if (t >= total) return;
  int e = (int)(t >> 3);
  int h = (int)(t & 7);
  int s = src[e], d = dst[e];
  unsafeAtomicAdd(&acc[(size_t)d * 8 + h], y[(size_t)s * 8 + h]);
}

__global__ void k_mid(const float* __restrict__ dis, float* __restrict__ y,
                      float* __restrict__ acc, const float* __restrict__ W2,
                      const float* __restrict__ b1, int n, int zero_acc) {
  __shared__ float sW[64];
  __shared__ float sb[8];
  if (threadIdx.x < 64) sW[threadIdx.x] = W2[threadIdx.x];
  if (threadIdx.x < 8)  sb[threadIdx.x] = b1[threadIdx.x];
  __syncthreads();
  int i = blockIdx.x * BLK + threadIdx.x;
  if (i >= n) return;
  float d = dis[i];
  float4* yp = (float4*)(y + (size_t)i * 8);
  float4* ap = (float4*)(acc + (size_t)i * 8);
  float4 y0 = yp[0], y1v = yp[1], a0 = ap[0], a1 = ap[1];
  float yy[8] = {y0.x,y0.y,y0.z,y0.w, y1v.x,y1v.y,y1v.z,y1v.w};
  float aa[8] = {a0.x,a0.y,a0.z,a0.w, a1.x,a1.y,a1.z,a1.w};
  float hv[8];
  #pragma unroll
  for (int jj = 0; jj < 8; ++jj) hv[jj] = fmaxf(fmaf(d, yy[jj] + aa[jj], sb[jj]), 0.f);
  float o[8];
  #pragma unroll
  for (int jj = 0; jj < 8; ++jj) {
    float s = 0.f;
    #pragma unroll
    for (int k = 0; k < 8; ++k) s = fmaf(hv[k], sW[k*8 + jj], s);
    o[jj] = d * s;
  }
  yp[0] = make_float4(o[0], o[1], o[2], o[3]);
  yp[1] = make_float4(o[4], o[5], o[6], o[7]);
  if (zero_acc) {
    ap[0] = make_float4(0.f, 0.f, 0.f, 0.f);
    ap[1] = make_float4(0.f, 0.f, 0.f, 0.f);
  }
}

__global__ void k_final(const float* __restrict__ dis, const float* __restrict__ y,
                        const float* __restrict__ acc, const float* __restrict__ b2,
                        const float* __restrict__ Wl, const int* __restrict__ batch,
                        float* __restrict__ zacc, int n) {
  __shared__ float sb[8], sw[8];
  if (threadIdx.x < 8) { sb[threadIdx.x] = b2[threadIdx.x]; sw[threadIdx.x] = Wl[threadIdx.x]; }
  __syncthreads();
  int i = blockIdx.x * BLK + threadIdx.x;
  float s = 0.f;
  int g = -1;
  if (i < n) {
    float d = dis[i];
    const float4* yp = (const float4*)(y + (size_t)i * 8);
    const float4* ap = (const float4*)(acc + (size_t)i * 8);
    float4 y0 = yp[0], y1v = yp[1], a0 = ap[0], a1 = ap[1];
    float yy[8] = {y0.x,y0.y,y0.z,y0.w, y1v.x,y1v.y,y1v.z,y1v.w};
    float aa[8] = {a0.x,a0.y,a0.z,a0.w, a1.x,a1.y,a1.z,a1.w};
    #pragma unroll
    for (int jj = 0; jj < 8; ++jj) {
      float h = fmaxf(fmaf(d, yy[jj] + aa[jj], sb[jj]), 0.f);
      s = fmaf(h, sw[jj], s);
    }
    g = batch[i];
  }
  int g0 = __shfl(g, 0);
  bool uni = __all(g == g0);
  if (uni) {
    #pragma unroll
    for (int off = 32; off > 0; off >>= 1) s += __shfl_down(s, off);
    if ((threadIdx.x & 63) == 0 && g0 >= 0) unsafeAtomicAdd(&zacc[g0], s);
  } else if (i < n) {
    unsafeAtomicAdd(&zacc[g], s);
  }
}

// ================= host =================

static inline size_t alignup(size_t v) { return (v + 255) & ~(size_t)255; }

extern "C" void kernel_launch(void* const* d_in, const int* in_sizes, int n_in,
                              void* d_out, int out_size, void* d_ws, size_t ws_size,
                              hipStream_t stream) {
  const float* x   = (const float*)d_in[0];
  const int*   ei  = (const int*)  d_in[1];
  const int*   bat = (const int*)  d_in[2];
  const float* W1  = (const float*)d_in[3];
  const float* b1  = (const float*)d_in[4];
  const float* W2  = (const float*)d_in[5];
  const float* b2  = (const float*)d_in[6];
  const float* Wl  = (const float*)d_in[7];
  const float* bl  = (const float*)d_in[8];
  float* out = (float*)d_out;

  int n  = in_sizes[0] / 16;   // 250000
  int E  = in_sizes[1] / 2;    // 8000000
  int ng = out_size;           // 512

  const int* src = ei;
  const int* dst = ei + E;

  int nb = (n + 255) >> 8;     // 977

  char* wsb = (char*)d_ws;
  size_t offY  = alignup((size_t)n * 4);                  // dis
  size_t offA  = offY + alignup((size_t)n * 8 * 4);       // y (f32 in fallback, bf16 uses half)
  size_t offZ  = offA + alignup((size_t)n * 8 * 4);       // acc / y2
  size_t offZn = offZ + alignup((size_t)ng * 4);          // zacc
  size_t offH  = offZn + alignup((size_t)n * 4);          // zn
  size_t offB  = offH + alignup((size_t)NBMAX * 4);       // ghist
  size_t offCu = offB + alignup((size_t)(NBMAX + 1) * 4); // base
  size_t offBn = offCu + alignup((size_t)NBMAX * 4);      // cursor
  size_t offRp = offBn + alignup((size_t)E * 4);          // binned
  size_t offCs = offRp + alignup(((size_t)n + 1) * 4);    // rowptr
  size_t need1 = offCs + alignup((size_t)E * 4);          // csr

  float*   dis    = (float*)wsb;
  int*     deg    = (int*)wsb;
  float*   y      = (float*)(wsb + offY);
  ushortT* ybf    = (ushortT*)(wsb + offY);
  float*   acc    = (float*)(wsb + offA);
  ushortT* y2bf   = (ushortT*)(wsb + offA);
  float*   zacc   = (float*)(wsb + offZ);
  float*   zn     = (float*)(wsb + offZn);
  int*     ghist  = (int*)(wsb + offH);
  int*     base   = (int*)(wsb + offB);
  int*     cursor = (int*)(wsb + offCu);
  int*     binned = (int*)(wsb + offBn);
  int*     rowptr = (int*)(wsb + offRp);
  int*     csr    = (int*)(wsb + offCs);

  int gN = (n + BLK - 1) / BLK;
  int gG = (ng + BLK - 1) / BLK;
  int gW = (int)(((long long)n * 64 + BLK - 1) / BLK);   // wave-per-node

  bool ok_bin = (nb <= NBMAX) && (n < (1 << 23));
  bool tier1 = ok_bin && (ws_size >= need1);

  if (tier1) {
    int histChunk = 8192;
    int gHist = (int)(((long long)E + histChunk - 1) / histChunk);
    int gBin  = (int)(((long long)E + CH - 1) / CH);
    int gI0   = (NBMAX > ng ? NBMAX : ng) / BLK + 1;
    k_init0 <<<gI0, BLK, 0, stream>>>(ghist, zacc, rowptr, NBMAX, ng, n, E, 1);
    k_hist  <<<gHist, BLK, 0, stream>>>(dst, ghist, E, nb, histChunk);
    k_scan  <<<1, BLK, 0, stream>>>(ghist, base, cursor, nb, E);
    k_bin   <<<gBin, BLK, 0, stream>>>(src, dst, cursor, binned, E, nb);
    k_sortdis<<<nb, BLK, 0, stream>>>(base, binned, csr, rowptr, dis, n);
    k_y1b   <<<gN, BLK, 0, stream>>>(x, W1, dis, ybf, n);
    k_gmid  <<<gW, BLK, 0, stream>>>(rowptr, csr, ybf, y2bf, dis, W2, b1, n);
    k_gfin  <<<gW, BLK, 0, stream>>>(rowptr, csr, y2bf, dis, b2, Wl, zn, n);
    k_pool  <<<gN, BLK, 0, stream>>>(zn, bat, zacc, n);
  } else {
    int accn = n * 8;
    long long tot = (long long)E * 8;
    int gInit = (accn + BLK - 1) / BLK;
    int gE    = (E + BLK - 1) / BLK;
    int gS    = (int)((tot + BLK - 1) / BLK);
    k_init   <<<gInit, BLK, 0, stream>>>(deg, acc, zacc, n, accn, ng);
    k_deg    <<<gE, BLK, 0, stream>>>(dst, deg, E);
    k_y1     <<<gN, BLK, 0, stream>>>(x, W1, deg, y, n);
    k_scatter<<<gS, BLK, 0, stream>>>(src, dst, y, acc, tot);
    k_mid    <<<gN, BLK, 0, stream>>>(dis, y, acc, W2, b1, n, 1);
    k_scatter<<<gS, BLK, 0, stream>>>(src, dst, y, acc, tot);
    k_final  <<<gN, BLK, 0, stream>>>(dis, y, acc, b2, Wl, bat, zacc, n);
  }
  k_out<<<gG, BLK, 0, stream>>>(zacc, bl, out, ng);
}